// Round 2
// baseline (295.787 us; speedup 1.0000x reference)
//
#include <hip/hip_runtime.h>
#include <hip/hip_bf16.h>

// IndRNNv2: 2 layers of { lin = x @ w^T + b ; h_s = relu(lin_s + r*h_{s-1}) }
// SEQ=256, BATCH=32, IN=HID=1024.
// Strategy: bf16 hi/lo split GEMM (K tripled -> 3072) on MFMA for fp32-grade
// accuracy, sequential-scan kernels for the recurrence.
// A-side layout: [hi | lo | hi]; B-side layout: [hi | hi | lo]
//   => dot = hiA*hiB + loA*hiB + hiA*loB ~= A*B  (lo*lo term dropped).

#define SEQ   256
#define BATCH 32
#define M_    (SEQ*BATCH)   // 8192
#define K_    1024
#define KS    3072          // split K
#define N_    1024

typedef __attribute__((ext_vector_type(8))) short  short8;
typedef __attribute__((ext_vector_type(4))) float  floatx4;

// ---------------- f32 -> split bf16 ----------------
// WSIDE==0 (A operand): blocks [hi | lo | hi]
// WSIDE==1 (B operand): blocks [hi | hi | lo]
template <int WSIDE>
__global__ __launch_bounds__(256) void split_k(const float* __restrict__ src,
                                               __hip_bfloat16* __restrict__ dst,
                                               int nvec)
{
    int t = blockIdx.x * 256 + threadIdx.x;
    if (t >= nvec) return;
    int idx = t << 2;                       // 4 f32 per thread
    int row = idx >> 10, col = idx & 1023;  // source is [rows][1024]
    const float4 v = *reinterpret_cast<const float4*>(src + idx);
    float f[4] = {v.x, v.y, v.z, v.w};
    __hip_bfloat16 hi[4], lo[4];
#pragma unroll
    for (int i = 0; i < 4; ++i) {
        hi[i] = __float2bfloat16(f[i]);
        lo[i] = __float2bfloat16(f[i] - __bfloat162float(hi[i]));
    }
    size_t base = (size_t)row * KS + col;
    *reinterpret_cast<uint2*>(dst + base) = *reinterpret_cast<const uint2*>(hi);
    if (WSIDE == 0) {
        *reinterpret_cast<uint2*>(dst + base + 1024) = *reinterpret_cast<const uint2*>(lo);
        *reinterpret_cast<uint2*>(dst + base + 2048) = *reinterpret_cast<const uint2*>(hi);
    } else {
        *reinterpret_cast<uint2*>(dst + base + 1024) = *reinterpret_cast<const uint2*>(hi);
        *reinterpret_cast<uint2*>(dst + base + 2048) = *reinterpret_cast<const uint2*>(lo);
    }
}

// ---------------- GEMM: C[m][n] = sum_k A[m][k]*B[n][k] + bias[n] ----------------
// m97-style: 128x128 tile, BK=32, 4 waves (2x2), 4x4 frags of 16x16x32 MFMA,
// global_load_lds width-16 staging, 2 barriers per K-step.
#define TM 128
#define TN 128
#define TK 32

__global__ __launch_bounds__(256) void gemm_bt(
    const __hip_bfloat16* __restrict__ A,   // [M_][KS]
    const __hip_bfloat16* __restrict__ B,   // [N_][KS]
    const float* __restrict__ bias,         // [N_]
    float* __restrict__ C)                  // [M_][N_]
{
    __shared__ __hip_bfloat16 As[TM * TK];
    __shared__ __hip_bfloat16 Bs[TN * TK];

    const int t    = threadIdx.x;
    const int lane = t & 63;
    const int wv   = t >> 6;        // wave 0..3
    const int wr   = wv >> 1;       // wave row (2)
    const int wc   = wv & 1;        // wave col (2)
    const int m0   = blockIdx.y * TM;
    const int n0   = blockIdx.x * TN;
    const int fr   = lane & 15;           // fragment row/col within 16
    const int kb   = (lane >> 4) << 3;    // k-chunk base within 32 (0,8,16,24)

    floatx4 acc[4][4] = {};

    for (int kt = 0; kt < KS / TK; ++kt) {
        const int k0 = kt * TK;
        __syncthreads();   // prior iteration's ds_reads done before overwrite
#pragma unroll
        for (int i = 0; i < 2; ++i) {
            int chunk = wv * 128 + i * 64 + lane;    // 0..511, 16B each
            int row = chunk >> 2;
            int c8  = (chunk & 3) << 3;
            __builtin_amdgcn_global_load_lds(
                (__attribute__((address_space(1))) void*)(A + (size_t)(m0 + row) * KS + k0 + c8),
                (__attribute__((address_space(3))) void*)(&As[chunk * 8]), 16, 0, 0);
            __builtin_amdgcn_global_load_lds(
                (__attribute__((address_space(1))) void*)(B + (size_t)(n0 + row) * KS + k0 + c8),
                (__attribute__((address_space(3))) void*)(&Bs[chunk * 8]), 16, 0, 0);
        }
        __syncthreads();   // compiler drains vmcnt before barrier

        short8 af[4], bf[4];
#pragma unroll
        for (int i = 0; i < 4; ++i)
            af[i] = *reinterpret_cast<const short8*>(&As[(wr * 64 + i * 16 + fr) * TK + kb]);
#pragma unroll
        for (int j = 0; j < 4; ++j)
            bf[j] = *reinterpret_cast<const short8*>(&Bs[(wc * 64 + j * 16 + fr) * TK + kb]);
#pragma unroll
        for (int i = 0; i < 4; ++i)
#pragma unroll
            for (int j = 0; j < 4; ++j)
                acc[i][j] = __builtin_amdgcn_mfma_f32_16x16x32_bf16(af[i], bf[j], acc[i][j], 0, 0, 0);
    }

    // epilogue: C/D layout (16x16): col = lane&15, row = (lane>>4)*4 + reg
#pragma unroll
    for (int j = 0; j < 4; ++j) {
        const int col = n0 + wc * 64 + j * 16 + fr;
        const float bj = bias[col];
#pragma unroll
        for (int i = 0; i < 4; ++i) {
            const int row = m0 + wr * 64 + i * 16 + ((lane >> 4) << 2);
#pragma unroll
            for (int jj = 0; jj < 4; ++jj)
                C[(size_t)(row + jj) * N_ + col] = acc[i][j][jj] + bj;
        }
    }
}

// ---------------- sequential scan over S ----------------
// One thread per (b, n). LAYER==0: emit A-side split bf16 activations
// ([hi|lo|hi]) for the next GEMM + h0T. LAYER==1: write y1 in place + h1T.
template <int LAYER>
__global__ __launch_bounds__(64) void scan_k(
    float* __restrict__ lin,                 // [SEQ][BATCH][N_] (d_out y region)
    const float* __restrict__ rec,           // [2][N_]
    __hip_bfloat16* __restrict__ asplit,     // LAYER==0: [M_][KS]
    float* __restrict__ hT)                  // d_out + SEQ*BATCH*N_, [BATCH][2*N_]
{
    const int tid = blockIdx.x * 64 + threadIdx.x;   // 0..32767
    const int b = tid >> 10, n = tid & 1023;
    const float r = rec[LAYER * N_ + n];
    float h = 0.f;
#pragma unroll 8
    for (int s = 0; s < SEQ; ++s) {
        float l = lin[(size_t)s * (BATCH * N_) + tid];
        h = fmaxf(fmaf(r, h, l), 0.f);
        if (LAYER == 0) {
            size_t base = (size_t)(s * BATCH + b) * KS + n;
            __hip_bfloat16 hi = __float2bfloat16(h);
            __hip_bfloat16 lo = __float2bfloat16(h - __bfloat162float(hi));
            asplit[base]        = hi;   // A-side: [hi | lo | hi]
            asplit[base + 1024] = lo;
            asplit[base + 2048] = hi;
        } else {
            lin[(size_t)s * (BATCH * N_) + tid] = h;
        }
    }
    hT[(size_t)b * (2 * N_) + LAYER * N_ + n] = h;
}

// ---------------- launch ----------------
extern "C" void kernel_launch(void* const* d_in, const int* in_sizes, int n_in,
                              void* d_out, int out_size, void* d_ws, size_t ws_size,
                              hipStream_t stream)
{
    const float* x   = (const float*)d_in[0];
    const float* w0  = (const float*)d_in[1];
    const float* b0  = (const float*)d_in[2];
    const float* w1  = (const float*)d_in[3];
    const float* b1  = (const float*)d_in[4];
    const float* rec = (const float*)d_in[5];

    float* out = (float*)d_out;
    float* y   = out;                               // [SEQ][BATCH][N_] — lin scratch then final y1
    float* hT  = out + (size_t)SEQ * BATCH * N_;    // [BATCH][2*N_]

    __hip_bfloat16* A0 = (__hip_bfloat16*)d_ws;     // [M_][KS] = 50.3 MB (reused for layer-1 acts)
    __hip_bfloat16* W0 = A0 + (size_t)M_ * KS;      // 6.3 MB
    __hip_bfloat16* W1 = W0 + (size_t)N_ * KS;      // 6.3 MB  (total ~63 MB of ws)

    // 1. split inputs to bf16 hi/lo
    split_k<0><<<(M_ * K_ / 4 + 255) / 256, 256, 0, stream>>>(x,  A0, M_ * K_ / 4);
    split_k<1><<<(N_ * K_ / 4 + 255) / 256, 256, 0, stream>>>(w0, W0, N_ * K_ / 4);
    split_k<1><<<(N_ * K_ / 4 + 255) / 256, 256, 0, stream>>>(w1, W1, N_ * K_ / 4);

    // 2. lin0 = x @ w0^T + b0
    gemm_bt<<<dim3(N_ / TN, M_ / TM), 256, 0, stream>>>(A0, W0, b0, y);

    // 3. scan layer 0 -> A-side split acts (reuse A0) + h0T
    scan_k<0><<<(BATCH * N_) / 64, 64, 0, stream>>>(y, rec, A0, hT);

    // 4. lin1 = y0 @ w1^T + b1
    gemm_bt<<<dim3(N_ / TN, M_ / TM), 256, 0, stream>>>(A0, W1, b1, y);

    // 5. scan layer 1 -> y1 (in place) + h1T
    scan_k<1><<<(BATCH * N_) / 64, 64, 0, stream>>>(y, rec, nullptr, hT);
}

// Round 3
// 278.305 us; speedup vs baseline: 1.0628x; 1.0628x over previous
//
#include <hip/hip_runtime.h>
#include <hip/hip_bf16.h>

// IndRNNv2: 2 layers of { lin = x @ w^T + b ; h_s = relu(lin_s + r*h_{s-1}) }
// SEQ=256, BATCH=32, IN=HID=1024.
// Strategy: bf16 hi/lo split GEMM (K tripled -> 3072) on MFMA for fp32-grade
// accuracy, sequential-scan kernels for the recurrence.
// A-side layout: [hi | lo | hi]; B-side layout: [hi | hi | lo]
//   => dot = hiA*hiB + loA*hiB + hiA*loB ~= A*B  (lo*lo term dropped).
//
// R2->R3: XCD M-chunked block swizzle in gemm_bt. Default mapping put
// XCD = blockIdx %% 8 = N-tile, so every XCD streamed the whole 50 MB A
// through its 4 MB L2 (FETCH_SIZE 200 MB, L2-fill-bound at 2.9 TB/s).
// Remap so XCD k owns M-panels [8k,8k+8) x all N-panels: A fetched once.

#define SEQ   256
#define BATCH 32
#define M_    (SEQ*BATCH)   // 8192
#define K_    1024
#define KS    3072          // split K
#define N_    1024

typedef __attribute__((ext_vector_type(8))) short  short8;
typedef __attribute__((ext_vector_type(4))) float  floatx4;

// ---------------- f32 -> split bf16 ----------------
// WSIDE==0 (A operand): blocks [hi | lo | hi]
// WSIDE==1 (B operand): blocks [hi | hi | lo]
template <int WSIDE>
__global__ __launch_bounds__(256) void split_k(const float* __restrict__ src,
                                               __hip_bfloat16* __restrict__ dst,
                                               int nvec)
{
    int t = blockIdx.x * 256 + threadIdx.x;
    if (t >= nvec) return;
    int idx = t << 2;                       // 4 f32 per thread
    int row = idx >> 10, col = idx & 1023;  // source is [rows][1024]
    const float4 v = *reinterpret_cast<const float4*>(src + idx);
    float f[4] = {v.x, v.y, v.z, v.w};
    __hip_bfloat16 hi[4], lo[4];
#pragma unroll
    for (int i = 0; i < 4; ++i) {
        hi[i] = __float2bfloat16(f[i]);
        lo[i] = __float2bfloat16(f[i] - __bfloat162float(hi[i]));
    }
    size_t base = (size_t)row * KS + col;
    *reinterpret_cast<uint2*>(dst + base) = *reinterpret_cast<const uint2*>(hi);
    if (WSIDE == 0) {
        *reinterpret_cast<uint2*>(dst + base + 1024) = *reinterpret_cast<const uint2*>(lo);
        *reinterpret_cast<uint2*>(dst + base + 2048) = *reinterpret_cast<const uint2*>(hi);
    } else {
        *reinterpret_cast<uint2*>(dst + base + 1024) = *reinterpret_cast<const uint2*>(hi);
        *reinterpret_cast<uint2*>(dst + base + 2048) = *reinterpret_cast<const uint2*>(lo);
    }
}

// ---------------- GEMM: C[m][n] = sum_k A[m][k]*B[n][k] + bias[n] ----------------
// m97-style: 128x128 tile, BK=32, 4 waves (2x2), 4x4 frags of 16x16x32 MFMA,
// global_load_lds width-16 staging, 2 barriers per K-step.
#define TM 128
#define TN 128
#define TK 32
#define NXCD 8
#define NTILE_N (N_ / TN)            // 8
#define NTILE_M (M_ / TM)            // 64
#define NTILES  (NTILE_N * NTILE_M)  // 512 (== 8 * 64, %8 == 0 -> simple swizzle bijective)

__global__ __launch_bounds__(256) void gemm_bt(
    const __hip_bfloat16* __restrict__ A,   // [M_][KS]
    const __hip_bfloat16* __restrict__ B,   // [N_][KS]
    const float* __restrict__ bias,         // [N_]
    float* __restrict__ C)                  // [M_][N_]
{
    __shared__ __hip_bfloat16 As[TM * TK];
    __shared__ __hip_bfloat16 Bs[TN * TK];

    // XCD M-chunked swizzle: hardware XCD = blockIdx.x % 8. Give XCD k the
    // tile ids [k*64, (k+1)*64) = M-panels [8k, 8k+8) x all 8 N-panels.
    const int bid  = blockIdx.x;
    const int xcd  = bid & (NXCD - 1);
    const int slot = bid >> 3;                    // 0..63
    const int tile = xcd * (NTILES / NXCD) + slot;
    const int ty   = tile >> 3;                   // M-panel 0..63
    const int tx   = tile & 7;                    // N-panel 0..7

    const int t    = threadIdx.x;
    const int lane = t & 63;
    const int wv   = t >> 6;        // wave 0..3
    const int wr   = wv >> 1;       // wave row (2)
    const int wc   = wv & 1;        // wave col (2)
    const int m0   = ty * TM;
    const int n0   = tx * TN;
    const int fr   = lane & 15;           // fragment row/col within 16
    const int kb   = (lane >> 4) << 3;    // k-chunk base within 32 (0,8,16,24)

    floatx4 acc[4][4] = {};

    for (int kt = 0; kt < KS / TK; ++kt) {
        const int k0 = kt * TK;
        __syncthreads();   // prior iteration's ds_reads done before overwrite
#pragma unroll
        for (int i = 0; i < 2; ++i) {
            int chunk = wv * 128 + i * 64 + lane;    // 0..511, 16B each
            int row = chunk >> 2;
            int c8  = (chunk & 3) << 3;
            __builtin_amdgcn_global_load_lds(
                (__attribute__((address_space(1))) void*)(A + (size_t)(m0 + row) * KS + k0 + c8),
                (__attribute__((address_space(3))) void*)(&As[chunk * 8]), 16, 0, 0);
            __builtin_amdgcn_global_load_lds(
                (__attribute__((address_space(1))) void*)(B + (size_t)(n0 + row) * KS + k0 + c8),
                (__attribute__((address_space(3))) void*)(&Bs[chunk * 8]), 16, 0, 0);
        }
        __syncthreads();   // compiler drains vmcnt before barrier

        short8 af[4], bf[4];
#pragma unroll
        for (int i = 0; i < 4; ++i)
            af[i] = *reinterpret_cast<const short8*>(&As[(wr * 64 + i * 16 + fr) * TK + kb]);
#pragma unroll
        for (int j = 0; j < 4; ++j)
            bf[j] = *reinterpret_cast<const short8*>(&Bs[(wc * 64 + j * 16 + fr) * TK + kb]);
#pragma unroll
        for (int i = 0; i < 4; ++i)
#pragma unroll
            for (int j = 0; j < 4; ++j)
                acc[i][j] = __builtin_amdgcn_mfma_f32_16x16x32_bf16(af[i], bf[j], acc[i][j], 0, 0, 0);
    }

    // epilogue: C/D layout (16x16): col = lane&15, row = (lane>>4)*4 + reg
#pragma unroll
    for (int j = 0; j < 4; ++j) {
        const int col = n0 + wc * 64 + j * 16 + fr;
        const float bj = bias[col];
#pragma unroll
        for (int i = 0; i < 4; ++i) {
            const int row = m0 + wr * 64 + i * 16 + ((lane >> 4) << 2);
#pragma unroll
            for (int jj = 0; jj < 4; ++jj)
                C[(size_t)(row + jj) * N_ + col] = acc[i][j][jj] + bj;
        }
    }
}

// ---------------- sequential scan over S ----------------
// One thread per (b, n). LAYER==0: emit A-side split bf16 activations
// ([hi|lo|hi]) for the next GEMM + h0T. LAYER==1: write y1 in place + h1T.
template <int LAYER>
__global__ __launch_bounds__(64) void scan_k(
    float* __restrict__ lin,                 // [SEQ][BATCH][N_] (d_out y region)
    const float* __restrict__ rec,           // [2][N_]
    __hip_bfloat16* __restrict__ asplit,     // LAYER==0: [M_][KS]
    float* __restrict__ hT)                  // d_out + SEQ*BATCH*N_, [BATCH][2*N_]
{
    const int tid = blockIdx.x * 64 + threadIdx.x;   // 0..32767
    const int b = tid >> 10, n = tid & 1023;
    const float r = rec[LAYER * N_ + n];
    float h = 0.f;
#pragma unroll 8
    for (int s = 0; s < SEQ; ++s) {
        float l = lin[(size_t)s * (BATCH * N_) + tid];
        h = fmaxf(fmaf(r, h, l), 0.f);
        if (LAYER == 0) {
            size_t base = (size_t)(s * BATCH + b) * KS + n;
            __hip_bfloat16 hi = __float2bfloat16(h);
            __hip_bfloat16 lo = __float2bfloat16(h - __bfloat162float(hi));
            asplit[base]        = hi;   // A-side: [hi | lo | hi]
            asplit[base + 1024] = lo;
            asplit[base + 2048] = hi;
        } else {
            lin[(size_t)s * (BATCH * N_) + tid] = h;
        }
    }
    hT[(size_t)b * (2 * N_) + LAYER * N_ + n] = h;
}

// ---------------- launch ----------------
extern "C" void kernel_launch(void* const* d_in, const int* in_sizes, int n_in,
                              void* d_out, int out_size, void* d_ws, size_t ws_size,
                              hipStream_t stream)
{
    const float* x   = (const float*)d_in[0];
    const float* w0  = (const float*)d_in[1];
    const float* b0  = (const float*)d_in[2];
    const float* w1  = (const float*)d_in[3];
    const float* b1  = (const float*)d_in[4];
    const float* rec = (const float*)d_in[5];

    float* out = (float*)d_out;
    float* y   = out;                               // [SEQ][BATCH][N_] — lin scratch then final y1
    float* hT  = out + (size_t)SEQ * BATCH * N_;    // [BATCH][2*N_]

    __hip_bfloat16* A0 = (__hip_bfloat16*)d_ws;     // [M_][KS] = 50.3 MB (reused for layer-1 acts)
    __hip_bfloat16* W0 = A0 + (size_t)M_ * KS;      // 6.3 MB
    __hip_bfloat16* W1 = W0 + (size_t)N_ * KS;      // 6.3 MB  (total ~63 MB of ws)

    // 1. split inputs to bf16 hi/lo
    split_k<0><<<(M_ * K_ / 4 + 255) / 256, 256, 0, stream>>>(x,  A0, M_ * K_ / 4);
    split_k<1><<<(N_ * K_ / 4 + 255) / 256, 256, 0, stream>>>(w0, W0, N_ * K_ / 4);
    split_k<1><<<(N_ * K_ / 4 + 255) / 256, 256, 0, stream>>>(w1, W1, N_ * K_ / 4);

    // 2. lin0 = x @ w0^T + b0
    gemm_bt<<<NTILES, 256, 0, stream>>>(A0, W0, b0, y);

    // 3. scan layer 0 -> A-side split acts (reuse A0) + h0T
    scan_k<0><<<(BATCH * N_) / 64, 64, 0, stream>>>(y, rec, A0, hT);

    // 4. lin1 = y0 @ w1^T + b1
    gemm_bt<<<NTILES, 256, 0, stream>>>(A0, W1, b1, y);

    // 5. scan layer 1 -> y1 (in place) + h1T
    scan_k<1><<<(BATCH * N_) / 64, 64, 0, stream>>>(y, rec, nullptr, hT);
}